// Round 18
// baseline (219.153 us; speedup 1.0000x reference)
//
#include <hip/hip_runtime.h>
#include <math.h>

#define NB 8
#define NA 256
#define NBD 256
#define NC 64
#define NF 129

struct alignas(8) cpx { float re, im; };

// packed fp16 complex <-> fp32
union H2U { uint u; _Float16 h[2]; };
__device__ __forceinline__ uint pkc(float re, float im){
  H2U x; x.h[0] = (_Float16)re; x.h[1] = (_Float16)im; return x.u;
}
__device__ __forceinline__ cpx unpkc(uint u){
  H2U x; x.u = u; cpx c; c.re = (float)x.h[0]; c.im = (float)x.h[1]; return c;
}

__device__ __forceinline__ cpx cmul(cpx a, cpx b){
  cpx r;
  r.re = fmaf(a.re, b.re, -(a.im * b.im));
  r.im = fmaf(a.re, b.im,  a.im * b.re);
  return r;
}

// K1/K3 swizzle (fp32 cpx tile, 32 columns) — r11-measured clean.
__device__ __forceinline__ int PHY(int n, int g){
  return (n << 5) | ((g + n + (n >> 4)) & 31);
}

// K2 exchange-tile swizzle (packed uint [256][16] logical -> [128][32] phys).
__device__ __forceinline__ int PHYS(int r, int c){
  int p = ((r & 1) ^ ((r >> 4) & 1)) << 4;
  int s = (((r >> 1) + (r >> 5)) & 3) << 2;
  return ((r >> 1) << 5) | p | ((c & 12) ^ s) | (c & 3);
}

// k0w: repack W -> Wp[f][h][ka:256][c:16] packed-fp16, pre-scaled by 256
// (unscaled W sigma ~1.5e-5 is fp16-subnormal; x256 normalizes; 1/256 folds
// into K3's output scale). Block 0 also writes the twiddle table.
__global__ __launch_bounds__(256) void k0w_pack(const float* __restrict__ wre,
                                                const float* __restrict__ wim,
                                                uint* __restrict__ wp,
                                                float2* __restrict__ tw){
  const int blk = blockIdx.x;            // f*4 + h
  const int f = blk >> 2, h = blk & 3;
  const int tid = threadIdx.x;
  if (blk == 0){
    double ang = 6.283185307179586476925286766559 * (double)tid / 256.0;
    tw[tid] = make_float2((float)cos(ang), (float)sin(ang));
  }
  const int c = tid & 15, kb = tid >> 4;
  uint* dst = wp + (size_t)blk * 4096;
  #pragma unroll
  for (int it = 0; it < 16; ++it){
    int ka = kb + 16*it;
    size_t src = ((size_t)ka*NF + f)*64 + h*16 + c;
    dst[ka*16 + c] = pkc(wre[src] * 256.0f, wim[src] * 256.0f);
  }
}

// In-register 16-point FFT, SIGN=-1 forward / +1 inverse (unnormalized).
template<int SIGN>
__device__ __forceinline__ void fft16(cpx a[16]){
  cpx tmp;
  #define SW(i,j) tmp = a[i]; a[i] = a[j]; a[j] = tmp;
  SW(1,8) SW(2,4) SW(3,12) SW(5,10) SW(7,14) SW(11,13)
  #undef SW
  const float CT[8] = {1.f, 0.92387953251128674f, 0.70710678118654752f, 0.38268343236508977f,
                       0.f, -0.38268343236508977f, -0.70710678118654752f, -0.92387953251128674f};
  const float ST[8] = {0.f, 0.38268343236508977f, 0.70710678118654752f, 0.92387953251128674f,
                       1.f, 0.92387953251128674f, 0.70710678118654752f, 0.38268343236508977f};
  #pragma unroll
  for (int s = 1; s <= 4; ++s){
    const int m = 1 << s, half = m >> 1, str = 16 >> s;
    #pragma unroll
    for (int k = 0; k < 16; k += m){
      #pragma unroll
      for (int j = 0; j < half; ++j){
        cpx w; w.re = CT[j*str]; w.im = (float)SIGN * ST[j*str];
        cpx t = cmul(a[k+j+half], w);
        cpx u = a[k+j];
        a[k+j].re      = u.re + t.re; a[k+j].im      = u.im + t.im;
        a[k+j+half].re = u.re - t.re; a[k+j+half].im = u.im - t.im;
      }
    }
  }
}

// 256-pt FFT on fp32 32-col tile, column g (K1/K3). Columns are wave-private
// (wave w owns g=4w..4w+3): intra-FFT exchanges need only wave_barrier.
template<int SIGN>
__device__ __forceinline__ void fft256_col(cpx* __restrict__ tile, int g, int t,
                                           const float2* __restrict__ tw){
  cpx a[16];
  #pragma unroll
  for (int n1 = 0; n1 < 16; ++n1) a[n1] = tile[PHY(16*n1 + t, g)];
  fft16<SIGN>(a);
  #pragma unroll
  for (int k1 = 1; k1 < 16; ++k1){
    float2 tv = tw[(t * k1) & 255];
    cpx w; w.re = tv.x; w.im = (SIGN < 0) ? -tv.y : tv.y;
    a[k1] = cmul(a[k1], w);
  }
  #pragma unroll
  for (int k1 = 0; k1 < 16; ++k1) tile[PHY(16*k1 + t, g)] = a[k1];
  __builtin_amdgcn_wave_barrier();

  cpx b[16];
  #pragma unroll
  for (int n2 = 0; n2 < 16; ++n2) b[n2] = tile[PHY(16*t + n2, g)];
  fft16<SIGN>(b);
  __builtin_amdgcn_wave_barrier();
  #pragma unroll
  for (int k2 = 0; k2 < 16; ++k2) tile[PHY(t + 16*k2, g)] = b[k2];
  __syncthreads();
}

// mid layout (packed fp16 cpx, uint each): [bb][f][h:4][a:256][c:16].

// K1 (r11-measured): rfft along b per (batch, a) row-tile; channel pairs
// packed as complex; fully-contiguous 64KB x read per block.
__global__ __launch_bounds__(512) void k1_rfft_b(const float* __restrict__ x,
                                                 uint2* __restrict__ mid_p2,
                                                 const float2* __restrict__ tw){
  __shared__ cpx tile[256*32];
  const int tid = threadIdx.x;
  const int blk = blockIdx.x;            // bb*256 + a
  const int bb = blk >> 8, a = blk & 255;
  const int g = tid >> 4, t = tid & 15;

  const float4* src = (const float4*)(x + (size_t)blk * (NBD * NC));
  #pragma unroll
  for (int it = 0; it < 8; ++it){
    int idx = it*512 + tid;          // float4 index into [256][16] (contiguous)
    int j = idx >> 4, q = idx & 15;
    float4 v = src[idx];
    cpx p0; p0.re = v.x; p0.im = v.y;
    cpx p1; p1.re = v.z; p1.im = v.w;
    tile[PHY(j, 2*q)]   = p0;
    tile[PHY(j, 2*q+1)] = p1;
  }
  __syncthreads();

  fft256_col<-1>(tile, g, t, tw);

  for (int it = 0; it < 9; ++it){
    int idx = it*512 + tid;
    if (idx < NF*32){
      int k = idx >> 5, gg = idx & 31;
      cpx zk = tile[PHY(k, gg)];
      cpx zm = tile[PHY((256 - k) & 255, gg)];
      float Ar = 0.5f*(zk.re + zm.re);
      float Ai = 0.5f*(zk.im - zm.im);
      float Br = 0.5f*(zk.im + zm.im);
      float Bi = 0.5f*(zm.re - zk.re);
      size_t o = ((((size_t)bb*NF + k)*4 + (gg >> 3))*256 + a)*8 + (gg & 7);
      uint2 pv; pv.x = pkc(Ar, Ai); pv.y = pkc(Br, Bi);
      mid_p2[o] = pv;
    }
  }
}

// K2 lean (barrier-free): the 16KB slab is L2/L3-resident, so phase-A input
// comes DIRECTLY from global (wave's 64 lanes exactly cover sixteen 64B
// lines per load) and the output scatters directly from registers (same
// line-covering pattern). LDS holds only the two wave-private exchanges ->
// ZERO __syncthreads; waves fully decoupled. In-place safe: each wave
// reads/writes only its own 4 columns of the slab (column-disjoint).
__global__ __launch_bounds__(256)
void k2_fft_a_mul(uint* __restrict__ mid_u,
                  const uint* __restrict__ wp,
                  const float2* __restrict__ tw){
  __shared__ uint xch[256*16];
  const int tid = threadIdx.x;
  const int blk = blockIdx.x;            // f*32 + bb*4 + h
  const int f = blk >> 5;
  const int bb = (blk >> 2) & 7, h = blk & 3;
  const int g = tid >> 4, t = tid & 15;  // wave w owns cols 4w..4w+3

  uint* base_u = mid_u + ((((size_t)bb*NF + f)*4 + h) << 12);
  const uint* wslab = wp + ((size_t)(f*4 + h) << 12);

  // ---- forward phase A: stride-16 column gather direct from global
  cpx b[16];
  #pragma unroll
  for (int n1 = 0; n1 < 16; ++n1) b[n1] = unpkc(base_u[(16*n1 + t)*16 + g]);
  fft16<-1>(b);
  #pragma unroll
  for (int k1 = 1; k1 < 16; ++k1){
    float2 tv = tw[(t * k1) & 255];
    cpx w; w.re = tv.x; w.im = -tv.y;
    b[k1] = cmul(b[k1], w);
  }

  // ---- wave-local exchange 1 (column wave-private; DS pipe in-order)
  #pragma unroll
  for (int k1 = 0; k1 < 16; ++k1) xch[PHYS(16*k1 + t, g)] = pkc(b[k1].re, b[k1].im);
  __builtin_amdgcn_wave_barrier();
  #pragma unroll
  for (int n2 = 0; n2 < 16; ++n2) b[n2] = unpkc(xch[PHYS(16*t + n2, g)]);

  // ---- forward phase B -> S[t+16*k2] in registers
  fft16<-1>(b);

  // ---- spectral multiply from hot 16KB Wp slab (scaled W; unscale in K3)
  #pragma unroll
  for (int k2 = 0; k2 < 16; ++k2){
    cpx w = unpkc(wslab[(t + 16*k2)*16 + g]);
    b[k2] = cmul(b[k2], w);
  }

  // ---- inverse phase A (same stride-16 set), twiddle
  fft16<1>(b);
  #pragma unroll
  for (int k1 = 1; k1 < 16; ++k1){
    float2 tv = tw[(t * k1) & 255];
    cpx w; w.re = tv.x; w.im = tv.y;
    b[k1] = cmul(b[k1], w);
  }

  // ---- wave-local exchange 2
  __builtin_amdgcn_wave_barrier();
  #pragma unroll
  for (int k1 = 0; k1 < 16; ++k1) xch[PHYS(16*k1 + t, g)] = pkc(b[k1].re, b[k1].im);
  __builtin_amdgcn_wave_barrier();
  #pragma unroll
  for (int n2 = 0; n2 < 16; ++n2) b[n2] = unpkc(xch[PHYS(16*t + n2, g)]);

  // ---- inverse phase B; scatter-store y[t+16*k2] direct from registers
  fft16<1>(b);
  #pragma unroll
  for (int k2 = 0; k2 < 16; ++k2)
    base_u[(t + 16*k2)*16 + g] = pkc(b[k2].re, b[k2].im);
}

// K3 (r11-measured): irfft along b per (batch, a). DC/Nyquist imaginary
// parts dropped (c2r). Applies 1/(a*b) and the 1/256 W-prescale at the
// output store.
__global__ __launch_bounds__(512) void k3_irfft_b(const uint2* __restrict__ mid_p2,
                                                  float2* __restrict__ y2,
                                                  const float2* __restrict__ tw){
  __shared__ cpx tile[256*32];
  const int tid = threadIdx.x;
  const int blk = blockIdx.x;            // bb*256 + a
  const int bb = blk >> 8, a = blk & 255;
  const int g = tid >> 4, t = tid & 15;

  for (int it = 0; it < 9; ++it){
    int idx = it*512 + tid;
    if (idx < NF*32){
      int f = idx >> 5, gg = idx & 31;
      size_t o = ((((size_t)bb*NF + f)*4 + (gg >> 3))*256 + a)*8 + (gg & 7);
      uint2 pv = mid_p2[o];
      cpx A = unpkc(pv.x), B = unpkc(pv.y);
      cpx sd;
      if (f == 0 || f == 128){
        sd.re = A.re;                // Im(A), Im(B) dropped (c2r semantics)
        sd.im = B.re;
      } else {
        sd.re = A.re - B.im; sd.im = A.im + B.re;       // S[f] = A + iB
      }
      tile[PHY(f, gg)] = sd;
      if (f >= 1 && f <= 127){
        cpx se; se.re = A.re + B.im; se.im = B.re - A.im; // S[256-f]
        tile[PHY(256 - f, gg)] = se;
      }
    }
  }
  __syncthreads();

  fft256_col<+1>(tile, g, t, tw);

  const float SC = 5.9604644775390625e-08f;   // 1/65536 * 1/256 (W prescale)
  float2* dst = y2 + (size_t)blk * (256*32);
  #pragma unroll
  for (int it = 0; it < 16; ++it){
    int idx = it*512 + tid;
    int n = idx >> 5, gg = idx & 31;
    cpx v = tile[PHY(n, gg)];
    float2 o; o.x = v.re * SC; o.y = v.im * SC;
    dst[(size_t)n*32 + gg] = o;
  }
}

extern "C" void kernel_launch(void* const* d_in, const int* in_sizes, int n_in,
                              void* d_out, int out_size, void* d_ws, size_t ws_size,
                              hipStream_t stream){
  const float* x   = (const float*)d_in[0];
  const float* wre = (const float*)d_in[1];
  const float* wim = (const float*)d_in[2];

  float2* tw   = (float2*)d_ws;                        // 256 float2 = 2 KB
  uint*   wpck = (uint*)d_ws + 512;                    // Wp ~8.45 MB
  uint*   midu = wpck + (size_t)NF*4*4096;             // packed fp16 mid ~67.7 MB

  k0w_pack    <<<NF*4,   256, 0, stream>>>(wre, wim, wpck, tw);
  k1_rfft_b   <<<NB*NA,  512, 0, stream>>>(x, (uint2*)midu, tw);
  k2_fft_a_mul<<<NF*32,  256, 0, stream>>>(midu, wpck, tw);
  k3_irfft_b  <<<NB*NA,  512, 0, stream>>>((const uint2*)midu, (float2*)d_out, tw);
}

// Round 19
// 182.886 us; speedup vs baseline: 1.1983x; 1.1983x over previous
//
#include <hip/hip_runtime.h>
#include <math.h>

#define NB 8
#define NA 256
#define NBD 256
#define NC 64
#define NF 129

struct alignas(8) cpx { float re, im; };

// packed fp16 complex <-> fp32
union H2U { uint u; _Float16 h[2]; };
__device__ __forceinline__ uint pkc(float re, float im){
  H2U x; x.h[0] = (_Float16)re; x.h[1] = (_Float16)im; return x.u;
}
__device__ __forceinline__ cpx unpkc(uint u){
  H2U x; x.u = u; cpx c; c.re = (float)x.h[0]; c.im = (float)x.h[1]; return c;
}

__device__ __forceinline__ cpx cmul(cpx a, cpx b){
  cpx r;
  r.re = fmaf(a.re, b.re, -(a.im * b.im));
  r.im = fmaf(a.re, b.im,  a.im * b.re);
  return r;
}

// K1/K3 swizzle (fp32 cpx tile, 32 columns) — r11-measured clean.
__device__ __forceinline__ int PHY(int n, int g){
  return (n << 5) | ((g + n + (n >> 4)) & 31);
}

// K2 swizzle (packed uint tile [256][16] logical -> [128][32] physical).
__device__ __forceinline__ int PHYS(int r, int c){
  int p = ((r & 1) ^ ((r >> 4) & 1)) << 4;
  int s = (((r >> 1) + (r >> 5)) & 3) << 2;
  return ((r >> 1) << 5) | p | ((c & 12) ^ s) | (c & 3);
}

// k0w: repack W -> Wp[f][h][ka:256][c:16] packed-fp16, pre-scaled by 256
// (unscaled W sigma ~1.5e-5 is fp16-subnormal; x256 normalizes; 1/256 folds
// into K3's output scale). One contiguous 16KB slab per K2 block.
// Block 0 additionally writes the 256-entry twiddle table (double-computed,
// fp32-rounded).
__global__ __launch_bounds__(256) void k0w_pack(const float* __restrict__ wre,
                                                const float* __restrict__ wim,
                                                uint* __restrict__ wp,
                                                float2* __restrict__ tw){
  const int blk = blockIdx.x;            // f*4 + h
  const int f = blk >> 2, h = blk & 3;
  const int tid = threadIdx.x;
  if (blk == 0){
    double ang = 6.283185307179586476925286766559 * (double)tid / 256.0;
    tw[tid] = make_float2((float)cos(ang), (float)sin(ang));
  }
  const int c = tid & 15, kb = tid >> 4;
  uint* dst = wp + (size_t)blk * 4096;
  #pragma unroll
  for (int it = 0; it < 16; ++it){
    int ka = kb + 16*it;
    size_t src = ((size_t)ka*NF + f)*64 + h*16 + c;
    dst[ka*16 + c] = pkc(wre[src] * 256.0f, wim[src] * 256.0f);
  }
}

// In-register 16-point FFT, SIGN=-1 forward / +1 inverse (unnormalized).
template<int SIGN>
__device__ __forceinline__ void fft16(cpx a[16]){
  cpx tmp;
  #define SW(i,j) tmp = a[i]; a[i] = a[j]; a[j] = tmp;
  SW(1,8) SW(2,4) SW(3,12) SW(5,10) SW(7,14) SW(11,13)
  #undef SW
  const float CT[8] = {1.f, 0.92387953251128674f, 0.70710678118654752f, 0.38268343236508977f,
                       0.f, -0.38268343236508977f, -0.70710678118654752f, -0.92387953251128674f};
  const float ST[8] = {0.f, 0.38268343236508977f, 0.70710678118654752f, 0.92387953251128674f,
                       1.f, 0.92387953251128674f, 0.70710678118654752f, 0.38268343236508977f};
  #pragma unroll
  for (int s = 1; s <= 4; ++s){
    const int m = 1 << s, half = m >> 1, str = 16 >> s;
    #pragma unroll
    for (int k = 0; k < 16; k += m){
      #pragma unroll
      for (int j = 0; j < half; ++j){
        cpx w; w.re = CT[j*str]; w.im = (float)SIGN * ST[j*str];
        cpx t = cmul(a[k+j+half], w);
        cpx u = a[k+j];
        a[k+j].re      = u.re + t.re; a[k+j].im      = u.im + t.im;
        a[k+j+half].re = u.re - t.re; a[k+j+half].im = u.im - t.im;
      }
    }
  }
}

// 256-pt FFT on fp32 32-col tile, column g (K1/K3). Columns are wave-private
// (wave w owns g=4w..4w+3): intra-FFT exchanges need only wave_barrier.
template<int SIGN>
__device__ __forceinline__ void fft256_col(cpx* __restrict__ tile, int g, int t,
                                           const float2* __restrict__ tw){
  cpx a[16];
  #pragma unroll
  for (int n1 = 0; n1 < 16; ++n1) a[n1] = tile[PHY(16*n1 + t, g)];
  fft16<SIGN>(a);
  #pragma unroll
  for (int k1 = 1; k1 < 16; ++k1){
    float2 tv = tw[(t * k1) & 255];
    cpx w; w.re = tv.x; w.im = (SIGN < 0) ? -tv.y : tv.y;
    a[k1] = cmul(a[k1], w);
  }
  #pragma unroll
  for (int k1 = 0; k1 < 16; ++k1) tile[PHY(16*k1 + t, g)] = a[k1];
  __builtin_amdgcn_wave_barrier();

  cpx b[16];
  #pragma unroll
  for (int n2 = 0; n2 < 16; ++n2) b[n2] = tile[PHY(16*t + n2, g)];
  fft16<SIGN>(b);
  __builtin_amdgcn_wave_barrier();
  #pragma unroll
  for (int k2 = 0; k2 < 16; ++k2) tile[PHY(t + 16*k2, g)] = b[k2];
  __syncthreads();
}

// mid layout (packed fp16 cpx, uint each): [bb][f][h:4][a:256][c:16].

// K1 (r11-measured): rfft along b per (batch, a) row-tile; channel pairs
// packed as complex; fully-contiguous 64KB x read per block.
__global__ __launch_bounds__(512) void k1_rfft_b(const float* __restrict__ x,
                                                 uint2* __restrict__ mid_p2,
                                                 const float2* __restrict__ tw){
  __shared__ cpx tile[256*32];
  const int tid = threadIdx.x;
  const int blk = blockIdx.x;            // bb*256 + a
  const int bb = blk >> 8, a = blk & 255;
  const int g = tid >> 4, t = tid & 15;

  const float4* src = (const float4*)(x + (size_t)blk * (NBD * NC));
  #pragma unroll
  for (int it = 0; it < 8; ++it){
    int idx = it*512 + tid;          // float4 index into [256][16] (contiguous)
    int j = idx >> 4, q = idx & 15;
    float4 v = src[idx];
    cpx p0; p0.re = v.x; p0.im = v.y;
    cpx p1; p1.re = v.z; p1.im = v.w;
    tile[PHY(j, 2*q)]   = p0;
    tile[PHY(j, 2*q+1)] = p1;
  }
  __syncthreads();

  fft256_col<-1>(tile, g, t, tw);

  for (int it = 0; it < 9; ++it){
    int idx = it*512 + tid;
    if (idx < NF*32){
      int k = idx >> 5, gg = idx & 31;
      cpx zk = tile[PHY(k, gg)];
      cpx zm = tile[PHY((256 - k) & 255, gg)];
      float Ar = 0.5f*(zk.re + zm.re);
      float Ai = 0.5f*(zk.im - zm.im);
      float Br = 0.5f*(zk.im + zm.im);
      float Bi = 0.5f*(zm.re - zk.re);
      size_t o = ((((size_t)bb*NF + k)*4 + (gg >> 3))*256 + a)*8 + (gg & 7);
      uint2 pv; pv.x = pkc(Ar, Ai); pv.y = pkc(Br, Bi);
      mid_p2[o] = pv;
    }
  }
}

// K2 (r11/r17-measured single-tile form): FFT along a, W-mul from hot 16KB
// Wp slab, iFFT along a; staged uint4 coalescing both directions (r18
// post-mortem: staging IS the load-combining — do not remove); wave-sync
// exchanges; fused register middle; f-major grid.
__global__ __launch_bounds__(256)
void k2_fft_a_mul(uint* __restrict__ mid_u,
                  const uint* __restrict__ wp,
                  const float2* __restrict__ tw){
  __shared__ uint tile_u[256*16];
  const int tid = threadIdx.x;
  const int blk = blockIdx.x;            // f*32 + bb*4 + h
  const int f = blk >> 5;
  const int bb = (blk >> 2) & 7, h = blk & 3;
  const int g = tid >> 4, t = tid & 15;  // wave w owns cols 4w..4w+3

  uint* base_u = mid_u + ((((size_t)bb*NF + f)*4 + h) << 12);
  const uint* wslab = wp + ((size_t)(f*4 + h) << 12);

  const uint4* base4 = (const uint4*)base_u;
  #pragma unroll
  for (int it = 0; it < 4; ++it){
    int idx = it*256 + tid;
    int r = idx >> 2, q = idx & 3;
    uint4 v = base4[idx];
    *(uint4*)&tile_u[PHYS(r, 4*q)] = v;
  }
  __syncthreads();

  cpx b[16];
  #pragma unroll
  for (int n1 = 0; n1 < 16; ++n1) b[n1] = unpkc(tile_u[PHYS(16*n1 + t, g)]);
  fft16<-1>(b);
  #pragma unroll
  for (int k1 = 1; k1 < 16; ++k1){
    float2 tv = tw[(t * k1) & 255];
    cpx w; w.re = tv.x; w.im = -tv.y;
    b[k1] = cmul(b[k1], w);
  }

  #pragma unroll
  for (int k1 = 0; k1 < 16; ++k1) tile_u[PHYS(16*k1 + t, g)] = pkc(b[k1].re, b[k1].im);
  __builtin_amdgcn_wave_barrier();
  #pragma unroll
  for (int n2 = 0; n2 < 16; ++n2) b[n2] = unpkc(tile_u[PHYS(16*t + n2, g)]);

  fft16<-1>(b);

  #pragma unroll
  for (int k2 = 0; k2 < 16; ++k2){
    cpx w = unpkc(wslab[(t + 16*k2)*16 + g]);
    b[k2] = cmul(b[k2], w);
  }

  fft16<1>(b);
  #pragma unroll
  for (int k1 = 1; k1 < 16; ++k1){
    float2 tv = tw[(t * k1) & 255];
    cpx w; w.re = tv.x; w.im = tv.y;
    b[k1] = cmul(b[k1], w);
  }

  __builtin_amdgcn_wave_barrier();
  #pragma unroll
  for (int k1 = 0; k1 < 16; ++k1) tile_u[PHYS(16*k1 + t, g)] = pkc(b[k1].re, b[k1].im);
  __builtin_amdgcn_wave_barrier();
  #pragma unroll
  for (int n2 = 0; n2 < 16; ++n2) b[n2] = unpkc(tile_u[PHYS(16*t + n2, g)]);

  fft16<1>(b);
  #pragma unroll
  for (int k2 = 0; k2 < 16; ++k2) tile_u[PHYS(t + 16*k2, g)] = pkc(b[k2].re, b[k2].im);
  __syncthreads();

  uint4* ob = (uint4*)base_u;
  #pragma unroll
  for (int it = 0; it < 4; ++it){
    int idx = it*256 + tid;
    int r = idx >> 2, q = idx & 3;
    ob[idx] = *(const uint4*)&tile_u[PHYS(r, 4*q)];
  }
}

// K3 (r11-measured): irfft along b per (batch, a). DC/Nyquist imaginary
// parts dropped (c2r). Applies 1/(a*b) and the 1/256 W-prescale at the
// output store.
__global__ __launch_bounds__(512) void k3_irfft_b(const uint2* __restrict__ mid_p2,
                                                  float2* __restrict__ y2,
                                                  const float2* __restrict__ tw){
  __shared__ cpx tile[256*32];
  const int tid = threadIdx.x;
  const int blk = blockIdx.x;            // bb*256 + a
  const int bb = blk >> 8, a = blk & 255;
  const int g = tid >> 4, t = tid & 15;

  for (int it = 0; it < 9; ++it){
    int idx = it*512 + tid;
    if (idx < NF*32){
      int f = idx >> 5, gg = idx & 31;
      size_t o = ((((size_t)bb*NF + f)*4 + (gg >> 3))*256 + a)*8 + (gg & 7);
      uint2 pv = mid_p2[o];
      cpx A = unpkc(pv.x), B = unpkc(pv.y);
      cpx sd;
      if (f == 0 || f == 128){
        sd.re = A.re;                // Im(A), Im(B) dropped (c2r semantics)
        sd.im = B.re;
      } else {
        sd.re = A.re - B.im; sd.im = A.im + B.re;       // S[f] = A + iB
      }
      tile[PHY(f, gg)] = sd;
      if (f >= 1 && f <= 127){
        cpx se; se.re = A.re + B.im; se.im = B.re - A.im; // S[256-f]
        tile[PHY(256 - f, gg)] = se;
      }
    }
  }
  __syncthreads();

  fft256_col<+1>(tile, g, t, tw);

  const float SC = 5.9604644775390625e-08f;   // 1/65536 * 1/256 (W prescale)
  float2* dst = y2 + (size_t)blk * (256*32);
  #pragma unroll
  for (int it = 0; it < 16; ++it){
    int idx = it*512 + tid;
    int n = idx >> 5, gg = idx & 31;
    cpx v = tile[PHY(n, gg)];
    float2 o; o.x = v.re * SC; o.y = v.im * SC;
    dst[(size_t)n*32 + gg] = o;
  }
}

extern "C" void kernel_launch(void* const* d_in, const int* in_sizes, int n_in,
                              void* d_out, int out_size, void* d_ws, size_t ws_size,
                              hipStream_t stream){
  const float* x   = (const float*)d_in[0];
  const float* wre = (const float*)d_in[1];
  const float* wim = (const float*)d_in[2];

  float2* tw   = (float2*)d_ws;                        // 256 float2 = 2 KB
  uint*   wpck = (uint*)d_ws + 512;                    // Wp ~8.45 MB
  uint*   midu = wpck + (size_t)NF*4*4096;             // packed fp16 mid ~67.7 MB

  k0w_pack    <<<NF*4,   256, 0, stream>>>(wre, wim, wpck, tw);
  k1_rfft_b   <<<NB*NA,  512, 0, stream>>>(x, (uint2*)midu, tw);
  k2_fft_a_mul<<<NF*32,  256, 0, stream>>>(midu, wpck, tw);
  k3_irfft_b  <<<NB*NA,  512, 0, stream>>>((const uint2*)midu, (float2*)d_out, tw);
}

// Round 20
// 164.349 us; speedup vs baseline: 1.3335x; 1.1128x over previous
//
#include <hip/hip_runtime.h>
#include <math.h>

#define NB 8
#define NA 256
#define NBD 256
#define NC 64
#define NF 129

struct alignas(8) cpx { float re, im; };

// packed fp16 complex <-> fp32
union H2U { uint u; _Float16 h[2]; };
__device__ __forceinline__ uint pkc(float re, float im){
  H2U x; x.h[0] = (_Float16)re; x.h[1] = (_Float16)im; return x.u;
}
__device__ __forceinline__ cpx unpkc(uint u){
  H2U x; x.u = u; cpx c; c.re = (float)x.h[0]; c.im = (float)x.h[1]; return c;
}

__device__ __forceinline__ cpx cmul(cpx a, cpx b){
  cpx r;
  r.re = fmaf(a.re, b.re, -(a.im * b.im));
  r.im = fmaf(a.re, b.im,  a.im * b.re);
  return r;
}

// K1/K3 swizzle (fp32 cpx tile, 32 columns) — r11-measured clean.
__device__ __forceinline__ int PHY(int n, int g){
  return (n << 5) | ((g + n + (n >> 4)) & 31);
}

// K2 swizzle (packed uint tile [256][16] logical -> [128][32] physical).
__device__ __forceinline__ int PHYS(int r, int c){
  int p = ((r & 1) ^ ((r >> 4) & 1)) << 4;
  int s = (((r >> 1) + (r >> 5)) & 3) << 2;
  return ((r >> 1) << 5) | p | ((c & 12) ^ s) | (c & 3);
}

// k0w: repack W -> Wp[f][h][ka:256][c:16] packed-fp16, pre-scaled by 256
// (unscaled W sigma ~1.5e-5 is fp16-subnormal; x256 normalizes; 1/256 folds
// into K3's output scale). One contiguous 16KB slab per K2 block.
// Block 0 additionally writes the 256-entry twiddle table.
__global__ __launch_bounds__(256) void k0w_pack(const float* __restrict__ wre,
                                                const float* __restrict__ wim,
                                                uint* __restrict__ wp,
                                                float2* __restrict__ tw){
  const int blk = blockIdx.x;            // f*4 + h
  const int f = blk >> 2, h = blk & 3;
  const int tid = threadIdx.x;
  if (blk == 0){
    double ang = 6.283185307179586476925286766559 * (double)tid / 256.0;
    tw[tid] = make_float2((float)cos(ang), (float)sin(ang));
  }
  const int c = tid & 15, kb = tid >> 4;
  uint* dst = wp + (size_t)blk * 4096;
  #pragma unroll
  for (int it = 0; it < 16; ++it){
    int ka = kb + 16*it;
    size_t src = ((size_t)ka*NF + f)*64 + h*16 + c;
    dst[ka*16 + c] = pkc(wre[src] * 256.0f, wim[src] * 256.0f);
  }
}

// In-register 16-point FFT, SIGN=-1 forward / +1 inverse (unnormalized).
template<int SIGN>
__device__ __forceinline__ void fft16(cpx a[16]){
  cpx tmp;
  #define SW(i,j) tmp = a[i]; a[i] = a[j]; a[j] = tmp;
  SW(1,8) SW(2,4) SW(3,12) SW(5,10) SW(7,14) SW(11,13)
  #undef SW
  const float CT[8] = {1.f, 0.92387953251128674f, 0.70710678118654752f, 0.38268343236508977f,
                       0.f, -0.38268343236508977f, -0.70710678118654752f, -0.92387953251128674f};
  const float ST[8] = {0.f, 0.38268343236508977f, 0.70710678118654752f, 0.92387953251128674f,
                       1.f, 0.92387953251128674f, 0.70710678118654752f, 0.38268343236508977f};
  #pragma unroll
  for (int s = 1; s <= 4; ++s){
    const int m = 1 << s, half = m >> 1, str = 16 >> s;
    #pragma unroll
    for (int k = 0; k < 16; k += m){
      #pragma unroll
      for (int j = 0; j < half; ++j){
        cpx w; w.re = CT[j*str]; w.im = (float)SIGN * ST[j*str];
        cpx t = cmul(a[k+j+half], w);
        cpx u = a[k+j];
        a[k+j].re      = u.re + t.re; a[k+j].im      = u.im + t.im;
        a[k+j+half].re = u.re - t.re; a[k+j+half].im = u.im - t.im;
      }
    }
  }
}

// 256-pt FFT on fp32 32-col tile, column g (K1/K3). Columns are wave-private
// (wave w owns g=4w..4w+3): intra-FFT exchanges need only wave_barrier.
template<int SIGN>
__device__ __forceinline__ void fft256_col(cpx* __restrict__ tile, int g, int t,
                                           const float2* __restrict__ tw){
  cpx a[16];
  #pragma unroll
  for (int n1 = 0; n1 < 16; ++n1) a[n1] = tile[PHY(16*n1 + t, g)];
  fft16<SIGN>(a);
  #pragma unroll
  for (int k1 = 1; k1 < 16; ++k1){
    float2 tv = tw[(t * k1) & 255];
    cpx w; w.re = tv.x; w.im = (SIGN < 0) ? -tv.y : tv.y;
    a[k1] = cmul(a[k1], w);
  }
  #pragma unroll
  for (int k1 = 0; k1 < 16; ++k1) tile[PHY(16*k1 + t, g)] = a[k1];
  __builtin_amdgcn_wave_barrier();

  cpx b[16];
  #pragma unroll
  for (int n2 = 0; n2 < 16; ++n2) b[n2] = tile[PHY(16*t + n2, g)];
  fft16<SIGN>(b);
  __builtin_amdgcn_wave_barrier();
  #pragma unroll
  for (int k2 = 0; k2 < 16; ++k2) tile[PHY(t + 16*k2, g)] = b[k2];
  __syncthreads();
}

// mid layout (packed fp16 cpx, uint each): [bb][f][h:4][a:256][c:16].

// K1 (r11-measured): rfft along b per (batch, a) row-tile; channel pairs
// packed as complex; fully-contiguous 64KB x read per block.
__global__ __launch_bounds__(512) void k1_rfft_b(const float* __restrict__ x,
                                                 uint2* __restrict__ mid_p2,
                                                 const float2* __restrict__ tw){
  __shared__ cpx tile[256*32];
  const int tid = threadIdx.x;
  const int blk = blockIdx.x;            // bb*256 + a
  const int bb = blk >> 8, a = blk & 255;
  const int g = tid >> 4, t = tid & 15;

  const float4* src = (const float4*)(x + (size_t)blk * (NBD * NC));
  #pragma unroll
  for (int it = 0; it < 8; ++it){
    int idx = it*512 + tid;          // float4 index into [256][16] (contiguous)
    int j = idx >> 4, q = idx & 15;
    float4 v = src[idx];
    cpx p0; p0.re = v.x; p0.im = v.y;
    cpx p1; p1.re = v.z; p1.im = v.w;
    tile[PHY(j, 2*q)]   = p0;
    tile[PHY(j, 2*q+1)] = p1;
  }
  __syncthreads();

  fft256_col<-1>(tile, g, t, tw);

  for (int it = 0; it < 9; ++it){
    int idx = it*512 + tid;
    if (idx < NF*32){
      int k = idx >> 5, gg = idx & 31;
      cpx zk = tile[PHY(k, gg)];
      cpx zm = tile[PHY((256 - k) & 255, gg)];
      float Ar = 0.5f*(zk.re + zm.re);
      float Ai = 0.5f*(zk.im - zm.im);
      float Br = 0.5f*(zk.im + zm.im);
      float Bi = 0.5f*(zm.re - zk.re);
      size_t o = ((((size_t)bb*NF + k)*4 + (gg >> 3))*256 + a)*8 + (gg & 7);
      uint2 pv; pv.x = pkc(Ar, Ai); pv.y = pkc(Br, Bi);
      mid_p2[o] = pv;
    }
  }
}

// K2 (r17 + W-slab LDS staging): FFT along a, W-mul, iFFT along a.
// Both the mid slab AND the 16KB W slab are staged via coalesced uint4
// loads into LDS under the one existing barrier; the mid-chain W read
// becomes a <=2-way LDS access instead of a 16-line global gather
// (r18 post-mortem: per-lane 4B gathers serialize on the TA pipe).
__global__ __launch_bounds__(256)
void k2_fft_a_mul(uint* __restrict__ mid_u,
                  const uint* __restrict__ wp,
                  const float2* __restrict__ tw){
  __shared__ uint tile_u[256*16];
  __shared__ uint wtile[256*16];
  const int tid = threadIdx.x;
  const int blk = blockIdx.x;            // f*32 + bb*4 + h
  const int f = blk >> 5;
  const int bb = (blk >> 2) & 7, h = blk & 3;
  const int g = tid >> 4, t = tid & 15;  // wave w owns cols 4w..4w+3

  uint* base_u = mid_u + ((((size_t)bb*NF + f)*4 + h) << 12);
  const uint* wslab = wp + ((size_t)(f*4 + h) << 12);

  const uint4* base4 = (const uint4*)base_u;
  const uint4* w4    = (const uint4*)wslab;
  #pragma unroll
  for (int it = 0; it < 4; ++it){
    int idx = it*256 + tid;
    int r = idx >> 2, q = idx & 3;
    uint4 v  = base4[idx];
    uint4 wv = w4[idx];
    *(uint4*)&tile_u[PHYS(r, 4*q)] = v;
    *(uint4*)&wtile[PHYS(r, 4*q)]  = wv;
  }
  __syncthreads();

  cpx b[16];
  #pragma unroll
  for (int n1 = 0; n1 < 16; ++n1) b[n1] = unpkc(tile_u[PHYS(16*n1 + t, g)]);
  fft16<-1>(b);
  #pragma unroll
  for (int k1 = 1; k1 < 16; ++k1){
    float2 tv = tw[(t * k1) & 255];
    cpx w; w.re = tv.x; w.im = -tv.y;
    b[k1] = cmul(b[k1], w);
  }

  #pragma unroll
  for (int k1 = 0; k1 < 16; ++k1) tile_u[PHYS(16*k1 + t, g)] = pkc(b[k1].re, b[k1].im);
  __builtin_amdgcn_wave_barrier();
  #pragma unroll
  for (int n2 = 0; n2 < 16; ++n2) b[n2] = unpkc(tile_u[PHYS(16*t + n2, g)]);

  fft16<-1>(b);

  // ---- spectral multiply from LDS W tile (park-pattern, <=2-way banks)
  #pragma unroll
  for (int k2 = 0; k2 < 16; ++k2){
    cpx w = unpkc(wtile[PHYS(t + 16*k2, g)]);
    b[k2] = cmul(b[k2], w);
  }

  fft16<1>(b);
  #pragma unroll
  for (int k1 = 1; k1 < 16; ++k1){
    float2 tv = tw[(t * k1) & 255];
    cpx w; w.re = tv.x; w.im = tv.y;
    b[k1] = cmul(b[k1], w);
  }

  __builtin_amdgcn_wave_barrier();
  #pragma unroll
  for (int k1 = 0; k1 < 16; ++k1) tile_u[PHYS(16*k1 + t, g)] = pkc(b[k1].re, b[k1].im);
  __builtin_amdgcn_wave_barrier();
  #pragma unroll
  for (int n2 = 0; n2 < 16; ++n2) b[n2] = unpkc(tile_u[PHYS(16*t + n2, g)]);

  fft16<1>(b);
  #pragma unroll
  for (int k2 = 0; k2 < 16; ++k2) tile_u[PHYS(t + 16*k2, g)] = pkc(b[k2].re, b[k2].im);
  __syncthreads();

  uint4* ob = (uint4*)base_u;
  #pragma unroll
  for (int it = 0; it < 4; ++it){
    int idx = it*256 + tid;
    int r = idx >> 2, q = idx & 3;
    ob[idx] = *(const uint4*)&tile_u[PHYS(r, 4*q)];
  }
}

// K3 (r11-measured): irfft along b per (batch, a). DC/Nyquist imaginary
// parts dropped (c2r). Applies 1/(a*b) and the 1/256 W-prescale at the
// output store.
__global__ __launch_bounds__(512) void k3_irfft_b(const uint2* __restrict__ mid_p2,
                                                  float2* __restrict__ y2,
                                                  const float2* __restrict__ tw){
  __shared__ cpx tile[256*32];
  const int tid = threadIdx.x;
  const int blk = blockIdx.x;            // bb*256 + a
  const int bb = blk >> 8, a = blk & 255;
  const int g = tid >> 4, t = tid & 15;

  for (int it = 0; it < 9; ++it){
    int idx = it*512 + tid;
    if (idx < NF*32){
      int f = idx >> 5, gg = idx & 31;
      size_t o = ((((size_t)bb*NF + f)*4 + (gg >> 3))*256 + a)*8 + (gg & 7);
      uint2 pv = mid_p2[o];
      cpx A = unpkc(pv.x), B = unpkc(pv.y);
      cpx sd;
      if (f == 0 || f == 128){
        sd.re = A.re;                // Im(A), Im(B) dropped (c2r semantics)
        sd.im = B.re;
      } else {
        sd.re = A.re - B.im; sd.im = A.im + B.re;       // S[f] = A + iB
      }
      tile[PHY(f, gg)] = sd;
      if (f >= 1 && f <= 127){
        cpx se; se.re = A.re + B.im; se.im = B.re - A.im; // S[256-f]
        tile[PHY(256 - f, gg)] = se;
      }
    }
  }
  __syncthreads();

  fft256_col<+1>(tile, g, t, tw);

  const float SC = 5.9604644775390625e-08f;   // 1/65536 * 1/256 (W prescale)
  float2* dst = y2 + (size_t)blk * (256*32);
  #pragma unroll
  for (int it = 0; it < 16; ++it){
    int idx = it*512 + tid;
    int n = idx >> 5, gg = idx & 31;
    cpx v = tile[PHY(n, gg)];
    float2 o; o.x = v.re * SC; o.y = v.im * SC;
    dst[(size_t)n*32 + gg] = o;
  }
}

extern "C" void kernel_launch(void* const* d_in, const int* in_sizes, int n_in,
                              void* d_out, int out_size, void* d_ws, size_t ws_size,
                              hipStream_t stream){
  const float* x   = (const float*)d_in[0];
  const float* wre = (const float*)d_in[1];
  const float* wim = (const float*)d_in[2];

  float2* tw   = (float2*)d_ws;                        // 256 float2 = 2 KB
  uint*   wpck = (uint*)d_ws + 512;                    // Wp ~8.45 MB
  uint*   midu = wpck + (size_t)NF*4*4096;             // packed fp16 mid ~67.7 MB

  k0w_pack    <<<NF*4,   256, 0, stream>>>(wre, wim, wpck, tw);
  k1_rfft_b   <<<NB*NA,  512, 0, stream>>>(x, (uint2*)midu, tw);
  k2_fft_a_mul<<<NF*32,  256, 0, stream>>>(midu, wpck, tw);
  k3_irfft_b  <<<NB*NA,  512, 0, stream>>>((const uint2*)midu, (float2*)d_out, tw);
}